// Round 1
// 63.189 us; speedup vs baseline: 1.0037x; 1.0037x over previous
//
#include <hip/hip_runtime.h>
#include <hip/hip_bf16.h>
#include <math.h>

typedef __attribute__((ext_vector_type(8))) short short8;
typedef __attribute__((ext_vector_type(4))) float floatx4;

// LDS type-punning: barriers no longer separate these accesses, so defeat TBAA.
typedef unsigned int uint_a   __attribute__((may_alias));
typedef uint2        uint2_a  __attribute__((may_alias));
typedef uint4        uint4_a  __attribute__((may_alias));
typedef short8       short8_a __attribute__((may_alias));

static __device__ __forceinline__ unsigned short bfbits(float f) {
    __hip_bfloat16 h = __float2bfloat16(f);
    unsigned short u;
    __builtin_memcpy(&u, &h, 2);
    return u;
}
static __device__ __forceinline__ unsigned pack2(float lo, float hi) {
    return (unsigned)bfbits(lo) | ((unsigned)bfbits(hi) << 16);
}

// ---- LDS strides ----
#define SP_STR  136   // u16; A-tiles (basis/silu), b128 frag reads (proven)
#define SBN_STR 68    // u16; wave-private spline half-tile [64][68]
#define ST_STR  68    // f32; spline T tiles (gather banking proven at 68)
#define STB_STR 36    // f32; base T tile
#define SC_STR  132   // u8

// block (nb, s): rows [16nb,16nb+16), out cols [32s,32s+32).
// Wave w privately owns spline chunk cc = s + 4w (basis group w): it stages
// its own B half-tiles (k split 0..63 / 64..127 through one 64x68 buffer),
// runs all 16 MFMAs, and writes T_w. Only 2 barriers: sP/sC publish + gather.
// Base GEMM: waves 2,3; B-operand packed straight from registers (no LDS tile).
__global__ __launch_bounds__(256, 2) void kan_fused(
    const float* __restrict__ x,
    const float* __restrict__ bw,
    const float* __restrict__ sw,
    float* __restrict__ out)
{
    __shared__ short sP[5 * 16 * SP_STR];       // 21760 B
    __shared__ short sBn[4 * 64 * SBN_STR];     // 34816 B (4 wave-private half-tiles)
    __shared__ float sT[4 * 16 * ST_STR];       // 17408 B
    __shared__ float sTb[16 * STB_STR];         //  2304 B
    __shared__ unsigned char sC[16 * SC_STR];   //  2112 B  => 78400 B, 2 blocks/CU

    const int tid = threadIdx.x;
    const int nb  = blockIdx.x >> 2;
    const int s   = blockIdx.x & 3;
    const int n0  = nb * 16;

    const int w = tid >> 6, l = tid & 63;
    const int m = l & 15, q = l >> 4;

    // ---- front-issue all pre-barrier global loads (one latency exposure) ----
    const int r  = tid >> 4;
    const int i0 = (tid & 15) * 8;
    float v[8];
    *(float4*)(v)     = *(const float4*)(x + (n0 + r) * 128 + i0);
    *(float4*)(v + 4) = *(const float4*)(x + (n0 + r) * 128 + i0 + 4);

    const int cc = s + 4 * w;                      // this wave's spline chunk
    const float* swp = sw + cc * 64 + m * 4;
    float4 pre[16];
#pragma unroll
    for (int rr = 0; rr < 16; ++rr)                // half-1: rows 0..63, 4x16B/row-step
        pre[rr] = *(const float4*)(swp + (q + 4 * rr) * 1024);

    float4 bw8[8];
    if (w >= 2) {                                  // base B rows for cols 16(w-2)+m
        const float* bwp = bw + (32 * s + 16 * (w - 2) + m) * 128 + q * 8;
#pragma unroll
        for (int kk = 0; kk < 4; ++kk) {
            bw8[2 * kk]     = *(const float4*)(bwp + kk * 32);
            bw8[2 * kk + 1] = *(const float4*)(bwp + kk * 32 + 4);
        }
    }

    // ---- prologue: silu/u/c + basis for 16 rows x 128 feats (unchanged math) ----
    {
        float A5[5][8];
        unsigned char cc8[8];
#pragma unroll
        for (int i = 0; i < 8; ++i) {
            float xv = v[i];
            float si = xv / (1.0f + expf(-xv));
            float xn = fminf(fmaxf(xv, -1.0f), 1.0f);
            float t  = (xn + 2.2f) / 0.4f;        // (xn - G0)/H, bit-exact vs verified path
            float u  = t - floorf(t);
            int idx  = (int)floorf(t);
            idx = min(max(idx, 3), 7);
            cc8[i] = (unsigned char)(idx - 3);
            float u2 = u * u, u3 = u2 * u, om = 1.0f - u;
            A5[0][i] = om * om * om * (1.0f / 6.0f);
            A5[1][i] = 0.5f * u3 - u2 + (2.0f / 3.0f);
            A5[2][i] = -0.5f * u3 + 0.5f * u2 + 0.5f * u + (1.0f / 6.0f);
            A5[3][i] = u3 * (1.0f / 6.0f);
            A5[4][i] = si;
        }
#pragma unroll
        for (int g = 0; g < 5; ++g) {
            unsigned p0 = pack2(A5[g][0], A5[g][1]);
            unsigned p1 = pack2(A5[g][2], A5[g][3]);
            unsigned p2 = pack2(A5[g][4], A5[g][5]);
            unsigned p3 = pack2(A5[g][6], A5[g][7]);
            *(uint4_a*)(&sP[(g * 16 + r) * SP_STR + i0]) = make_uint4(p0, p1, p2, p3);
        }
        *(uint_a*)(&sC[r * SC_STR + i0])     = cc8[0] | (cc8[1]<<8) | (cc8[2]<<16) | (cc8[3]<<24);
        *(uint_a*)(&sC[r * SC_STR + i0 + 4]) = cc8[4] | (cc8[5]<<8) | (cc8[6]<<16) | (cc8[7]<<24);
    }

    // ---- cvt + write own half-tile (wave-private region: no barrier needed) ----
#pragma unroll
    for (int rr = 0; rr < 16; ++rr)
        *(uint2_a*)(&sBn[(w * 64 + q + 4 * rr) * SBN_STR + m * 4]) =
            make_uint2(pack2(pre[rr].x, pre[rr].y), pack2(pre[rr].z, pre[rr].w));

    __syncthreads();   // B1: sP/sC published (vmem also drains here, once)

    // issue own half-2 loads; latency hides under phase-1 MFMA
    float4 pre2[16];
#pragma unroll
    for (int rr = 0; rr < 16; ++rr)
        pre2[rr] = *(const float4*)(swp + (64 + q + 4 * rr) * 1024);

    const short* tile = &sBn[w * 64 * SBN_STR];
    const short* ap   = &sP[(w * 16 + m) * SP_STR + q * 8];
    floatx4 acc[4] = {{0.f,0.f,0.f,0.f},{0.f,0.f,0.f,0.f},
                      {0.f,0.f,0.f,0.f},{0.f,0.f,0.f,0.f}};

    // ---- phase 1: k = 0..63 (own tile holds rows 0..63) ----
#pragma unroll
    for (int kh = 0; kh < 2; ++kh) {
        short8 af = *(const short8_a*)(ap + kh * 32);
#pragma unroll
        for (int cg = 0; cg < 4; ++cg) {
            short8 bf;
#pragma unroll
            for (int j2 = 0; j2 < 8; ++j2)
                bf[j2] = tile[(kh * 32 + q * 8 + j2) * SBN_STR + cg * 16 + m];
            acc[cg] = __builtin_amdgcn_mfma_f32_16x16x32_bf16(af, bf, acc[cg], 0, 0, 0);
        }
    }

    // ---- cvt + overwrite own tile with rows 64..127 (same-wave DS is in-order) ----
#pragma unroll
    for (int rr = 0; rr < 16; ++rr)
        *(uint2_a*)(&sBn[(w * 64 + q + 4 * rr) * SBN_STR + m * 4]) =
            make_uint2(pack2(pre2[rr].x, pre2[rr].y), pack2(pre2[rr].z, pre2[rr].w));

    // ---- phase 2: k = 64..127 ----
#pragma unroll
    for (int kh = 0; kh < 2; ++kh) {
        short8 af = *(const short8_a*)(ap + (2 + kh) * 32);
#pragma unroll
        for (int cg = 0; cg < 4; ++cg) {
            short8 bf;
#pragma unroll
            for (int j2 = 0; j2 < 8; ++j2)
                bf[j2] = tile[(kh * 32 + q * 8 + j2) * SBN_STR + cg * 16 + m];
            acc[cg] = __builtin_amdgcn_mfma_f32_16x16x32_bf16(af, bf, acc[cg], 0, 0, 0);
        }
    }

    // ---- write spline T_w ----
#pragma unroll
    for (int cg = 0; cg < 4; ++cg)
#pragma unroll
        for (int rr = 0; rr < 4; ++rr)
            sT[(w * 16 + q * 4 + rr) * ST_STR + cg * 16 + m] = acc[cg][rr];

    // ---- base GEMM on waves 2,3: B packed straight from registers ----
    if (w >= 2) {
        const short* ap4 = &sP[(4 * 16 + m) * SP_STR + q * 8];
        floatx4 ab = {0.f, 0.f, 0.f, 0.f};
#pragma unroll
        for (int kk = 0; kk < 4; ++kk) {
            short8 af = *(const short8_a*)(ap4 + kk * 32);
            uint4 pb = make_uint4(pack2(bw8[2*kk].x,   bw8[2*kk].y),
                                  pack2(bw8[2*kk].z,   bw8[2*kk].w),
                                  pack2(bw8[2*kk+1].x, bw8[2*kk+1].y),
                                  pack2(bw8[2*kk+1].z, bw8[2*kk+1].w));
            short8 bf;
            __builtin_memcpy(&bf, &pb, 16);
            ab = __builtin_amdgcn_mfma_f32_16x16x32_bf16(af, bf, ab, 0, 0, 0);
        }
#pragma unroll
        for (int rr = 0; rr < 4; ++rr)
            sTb[(q * 4 + rr) * STB_STR + 16 * (w - 2) + m] = ab[rr];
    }

    __syncthreads();   // B3: all T ready

    // ---- gather + store (indexing identical to verified kernel) ----
    const int gn = tid >> 4, go2 = tid & 15;
    const int oh = 8 * s + (go2 >> 1);
    float racc0 = sTb[gn * STB_STR + 2 * go2];
    float racc1 = sTb[gn * STB_STR + 2 * go2 + 1];
#pragma unroll
    for (int j = 0; j < 4; ++j) {
        int c   = sC[gn * SC_STR + 32 * j + oh];
        int rel = 8 * (go2 >> 1) + c + 2 * (go2 & 1);
        racc0 += sT[(j * 16 + gn) * ST_STR + rel];
        racc1 += sT[(j * 16 + gn) * ST_STR + rel + 1];
    }
    *(float2*)(out + (n0 + gn) * 128 + 32 * s + 2 * go2) = make_float2(racc0, racc1);
}

extern "C" void kernel_launch(void* const* d_in, const int* in_sizes, int n_in,
                              void* d_out, int out_size, void* d_ws, size_t ws_size,
                              hipStream_t stream) {
    const float* x  = (const float*)d_in[0];
    const float* bw = (const float*)d_in[1];
    const float* sw = (const float*)d_in[2];
    float* out = (float*)d_out;
    kan_fused<<<dim3(512), dim3(256), 0, stream>>>(x, bw, sw, out);
}